// Round 2
// baseline (111.207 us; speedup 1.0000x reference)
//
#include <hip/hip_runtime.h>

// Hadamard transform along channel dim of NCHW fp32 tensor (FWHT_1024 = H_32 (x) H_32).
// x: [32, 1024, 32, 32] fp32; out[b,d,s] = sum_c x[b,c,s] * (-1)^popc(c&d) / 32.
//
// R2: persistent blocks (2/CU) + register double-buffer prefetch + raw barriers
// that wait only on lgkmcnt (LDS), so prefetch loads & streaming stores stay in
// flight across barriers (hipcc's __syncthreads drains vmcnt(0) -- avoided here).
//
// LDS swizzle: channel c=(i<<5)|j stored at slot (i<<5)|(j^i) -> every LDS access
// pattern in both passes is exactly 2-way bank aliased (free on CDNA4). Verified
// R1: SQ_LDS_BANK_CONFLICT == 0.

constexpr int C       = 1024;
constexpr int SPATIAL = 1024;   // 32*32, contiguous innermost
constexpr int S       = 16;     // spatial positions per chunk (64B per channel row)
constexpr int BLOCK   = 512;
constexpr int CHUNKS_PER_BLOCK = 4;   // consecutive -> 256B contiguous stripe per channel
constexpr int GRID    = 32 * (SPATIAL / S) / CHUNKS_PER_BLOCK;   // 512 = 2 blocks/CU

__device__ __forceinline__ void lds_barrier() {
    // Wait only for LDS ops; do NOT drain vmcnt (prefetch loads / streaming stores).
    asm volatile("s_waitcnt lgkmcnt(0)" ::: "memory");
    __builtin_amdgcn_s_barrier();
}

__global__ __launch_bounds__(BLOCK, 4) void hadamard_fwht_kernel(
    const float* __restrict__ x, float* __restrict__ out)
{
    __shared__ float lds[C * S];   // 64 KiB -> 2 blocks/CU

    const int t  = threadIdx.x;
    const int g0 = blockIdx.x * CHUNKS_PER_BLOCK;

    float4 r[8];   // prefetch buffer: this thread's 128B of the chunk

    auto issue_loads = [&](int g) {
        const int b = g >> 6, chunk = g & 63;
        const size_t base = ((size_t)b * C) * SPATIAL + (size_t)chunk * S;
        #pragma unroll
        for (int k = 0; k < 8; ++k) {
            const int idx4 = t + (k << 9);          // [0, 4096)
            const int c    = idx4 >> 2;
            const int s4   = idx4 & 3;
            r[k] = *reinterpret_cast<const float4*>(
                x + base + (size_t)c * SPATIAL + (s4 << 2));
        }
    };

    issue_loads(g0);

    for (int it = 0; it < CHUNKS_PER_BLOCK; ++it) {
        const int g = g0 + it;
        const int b = g >> 6, chunk = g & 63;
        const size_t base = ((size_t)b * C) * SPATIAL + (size_t)chunk * S;

        // ---- commit prefetched regs -> LDS (swizzled) ----
        #pragma unroll
        for (int k = 0; k < 8; ++k) {
            const int idx4 = t + (k << 9);
            const int c    = idx4 >> 2;
            const int s4   = idx4 & 3;
            const int i    = c >> 5;
            const int j    = c & 31;
            const int cs   = (i << 5) | (j ^ i);
            *reinterpret_cast<float4*>(&lds[(cs << 4) + (s4 << 2)]) = r[k];
        }
        lds_barrier();

        // ---- prefetch next chunk (overlaps pass1+pass2 compute) ----
        if (it + 1 < CHUNKS_PER_BLOCK) issue_loads(g + 1);

        float v[32];

        // ---- pass 1: FWHT_32 along i; thread (j,s) reads+writes its own slots ----
        {
            const int j = t >> 4;
            const int s = t & 15;
            #pragma unroll
            for (int i = 0; i < 32; ++i)
                v[i] = lds[(((i << 5) | (j ^ i)) << 4) + s];

            #pragma unroll
            for (int m = 1; m < 32; m <<= 1)
                #pragma unroll
                for (int gg = 0; gg < 32; gg += (m << 1))
                    #pragma unroll
                    for (int a = gg; a < gg + m; ++a) {
                        const float p = v[a], q = v[a + m];
                        v[a]     = p + q;
                        v[a + m] = p - q;
                    }

            #pragma unroll
            for (int i = 0; i < 32; ++i)
                lds[(((i << 5) | (j ^ i)) << 4) + s] = v[i];
        }
        lds_barrier();

        // ---- pass 2: FWHT_32 along j; scale 1/32; streaming store ----
        {
            const int i = t >> 4;
            const int s = t & 15;
            #pragma unroll
            for (int j = 0; j < 32; ++j)
                v[j] = lds[(((i << 5) | (j ^ i)) << 4) + s];

            #pragma unroll
            for (int m = 1; m < 32; m <<= 1)
                #pragma unroll
                for (int gg = 0; gg < 32; gg += (m << 1))
                    #pragma unroll
                    for (int a = gg; a < gg + m; ++a) {
                        const float p = v[a], q = v[a + m];
                        v[a]     = p + q;
                        v[a + m] = p - q;
                    }

            const float scale = 1.0f / 32.0f;
            float* o = out + base + ((size_t)(i << 5)) * SPATIAL + s;
            #pragma unroll
            for (int j = 0; j < 32; ++j)
                __builtin_nontemporal_store(v[j] * scale, &o[(size_t)j * SPATIAL]);
        }
        lds_barrier();   // protect LDS from next iteration's writes
    }
}

extern "C" void kernel_launch(void* const* d_in, const int* in_sizes, int n_in,
                              void* d_out, int out_size, void* d_ws, size_t ws_size,
                              hipStream_t stream) {
    const float* x = (const float*)d_in[0];
    float* out = (float*)d_out;
    hadamard_fwht_kernel<<<dim3(GRID), dim3(BLOCK), 0, stream>>>(x, out);
}